// Round 2
// baseline (353.318 us; speedup 1.0000x reference)
//
#include <hip/hip_runtime.h>
#include <stdint.h>

// ---------------------------------------------------------------------------
// LocalAtomAttention on gfx950 — round 2.
//   Fused QKV proj (bf16 MFMA) -> IN-REGISTER per-residue attention
//   (shfl butterfly, no LDS) -> out proj. Only O round-trips LDS (16 KB,
//   XOR-swizzled). One barrier total. 3 blocks/CU target.
// Key layout fact: MFMA C-layout (col=lane&15, row=quad*4+reg) puts all 4
// atoms of residue (m*4+quad) in ONE lane, and head h's 32 channels in wave h.
// ---------------------------------------------------------------------------

typedef __bf16 bf16x8 __attribute__((ext_vector_type(8)));
typedef float  f32x4  __attribute__((ext_vector_type(4)));

#define N_RES 65536   // B*L
#define RPB   16      // residues per block
#define MROWS 64      // atom rows per block
#define CDIM  128

__device__ __forceinline__ uint32_t pk2(float a, float b) {
    uint32_t ua = __builtin_bit_cast(uint32_t, a) + 0x8000u;
    uint32_t ub = __builtin_bit_cast(uint32_t, b) + 0x8000u;
    return (ua >> 16) | (ub & 0xffff0000u);
}
__device__ __forceinline__ uint16_t bf1(float a) {
    return (uint16_t)((__builtin_bit_cast(uint32_t, a) + 0x8000u) >> 16);
}
__device__ __forceinline__ bf16x8 pack8(float4 f0, float4 f1) {
    uint4 uu = make_uint4(pk2(f0.x, f0.y), pk2(f0.z, f0.w),
                          pk2(f1.x, f1.y), pk2(f1.z, f1.w));
    return __builtin_bit_cast(bf16x8, uu);
}
// bit-permuted swizzle key of (row&15): [r1,q1,q0,r0] -> spreads all varying
// lane bits into distinct LDS banks for the C-layout u16 scatter.
__device__ __forceinline__ int swz_key(int row4) {
    return ((row4 & 2) << 2) | ((row4 & 8) >> 1) | ((row4 & 4) >> 1) | (row4 & 1);
}

// --------------------------- W fp32 -> bf16 pre-pass ------------------------
__global__ void wconv_kernel(const float* __restrict__ wq, const float* __restrict__ wk,
                             const float* __restrict__ wv, const float* __restrict__ wo,
                             uint16_t* __restrict__ dst) {
    int gid = blockIdx.x * 256 + threadIdx.x;   // 16384 threads x 4 elems
    int idx = gid * 4;
    int sel = idx >> 14;
    int off = idx & 16383;
    const float* s = (sel == 0) ? wq : (sel == 1) ? wk : (sel == 2) ? wv : wo;
    float4 f = *(const float4*)(s + off);
    uint2 u = make_uint2(pk2(f.x, f.y), pk2(f.z, f.w));
    *(uint2*)(dst + idx) = u;
}

// --------------------------------- main -------------------------------------
template <bool USEWS>
__global__ __launch_bounds__(256, 3)
void laa_main(const float* __restrict__ x, const int* __restrict__ mask,
              const float* __restrict__ Wq, const float* __restrict__ bq,
              const float* __restrict__ Wk, const float* __restrict__ bk,
              const float* __restrict__ Wv, const float* __restrict__ bv,
              const float* __restrict__ Wo, const float* __restrict__ bo,
              const uint16_t* __restrict__ wbf,
              float* __restrict__ out) {
    __shared__ uint16_t sO[MROWS * CDIM];   // 16 KB, XOR-swizzled

    const int tid  = threadIdx.x;
    const int wave = tid >> 6;        // == head; owns cols [wave*32, wave*32+32)
    const int lane = tid & 63;
    const int lrow = lane & 15;
    const int quad = lane >> 4;
    const long m0  = (long)blockIdx.x * MROWS;

    const f32x4 vzero = {0.f, 0.f, 0.f, 0.f};
    const float SC = 0.17677669529663689f;   // 1/sqrt(32)

    // per-lane bias values for this lane's two columns (nt=0,1)
    const int c0 = wave * 32 + lrow, c1 = c0 + 16;
    const float bq0 = bq[c0], bq1 = bq[c1];
    const float bk0 = bk[c0], bk1 = bk[c1];
    const float bv0 = bv[c0], bv1 = bv[c1];

    // ---- fused Q/K/V GEMMs, N split across waves ---------------------------
    f32x4 acc[3][4][2];  // [qkv][m-tile][nt]
    #pragma unroll
    for (int g = 0; g < 3; ++g)
        #pragma unroll
        for (int m = 0; m < 4; ++m)
            #pragma unroll
            for (int nt = 0; nt < 2; ++nt) acc[g][m][nt] = vzero;

    const float* wsrc32[3] = {Wq, Wk, Wv};
    #pragma unroll
    for (int ks = 0; ks < 4; ++ks) {
        bf16x8 af[4];
        #pragma unroll
        for (int m = 0; m < 4; ++m) {
            const float4* p = (const float4*)(x + (m0 + m * 16 + lrow) * CDIM + ks * 32 + quad * 8);
            af[m] = pack8(p[0], p[1]);
        }
        bf16x8 bfr[3][2];
        #pragma unroll
        for (int g = 0; g < 3; ++g) {
            #pragma unroll
            for (int nt = 0; nt < 2; ++nt) {
                int wrow = wave * 32 + nt * 16 + lrow;
                if constexpr (USEWS) {
                    bfr[g][nt] = *(const bf16x8*)(wbf + g * 16384 + wrow * CDIM + ks * 32 + quad * 8);
                } else {
                    const float* wp = wsrc32[g] + wrow * CDIM + ks * 32 + quad * 8;
                    bfr[g][nt] = pack8(((const float4*)wp)[0], ((const float4*)wp)[1]);
                }
            }
        }
        #pragma unroll
        for (int g = 0; g < 3; ++g)
            #pragma unroll
            for (int m = 0; m < 4; ++m)
                #pragma unroll
                for (int nt = 0; nt < 2; ++nt)
                    acc[g][m][nt] = __builtin_amdgcn_mfma_f32_16x16x32_bf16(
                        af[m], bfr[g][nt], acc[g][m][nt], 0, 0, 0);
    }

    // ---- in-register attention (residue m*4+quad lives in this lane) -------
    // sO write address pieces (constant across m)
    const int key_w = swz_key(quad * 4);            // row&15 = quad*4+r; fold r below
    #pragma unroll
    for (int m = 0; m < 4; ++m) {
        const int4 mk = *(const int4*)(mask + ((long)blockIdx.x * RPB + m * 4 + quad) * 4);
        const int mka[4] = {mk.x, mk.y, mk.z, mk.w};

        float qv[4][2], kv[4][2], vv[4][2];
        #pragma unroll
        for (int r = 0; r < 4; ++r) {
            qv[r][0] = (acc[0][m][0][r] + bq0) * SC;
            qv[r][1] = (acc[0][m][1][r] + bq1) * SC;
            kv[r][0] =  acc[1][m][0][r] + bk0;
            kv[r][1] =  acc[1][m][1][r] + bk1;
            vv[r][0] =  acc[2][m][0][r] + bv0;
            vv[r][1] =  acc[2][m][1][r] + bv1;
        }
        // partial (scaled) scores over this lane's 2 head-dims
        float t[16];
        #pragma unroll
        for (int qa = 0; qa < 4; ++qa)
            #pragma unroll
            for (int ka = 0; ka < 4; ++ka)
                t[qa * 4 + ka] = qv[qa][0] * kv[ka][0] + qv[qa][1] * kv[ka][1];
        // butterfly over the 16 lanes sharing this quad -> full 32-dim dots
        #pragma unroll
        for (int s = 1; s < 16; s <<= 1)
            #pragma unroll
            for (int i = 0; i < 16; ++i)
                t[i] += __shfl_xor(t[i], s, 16);

        // masked softmax (replicated across the 16 lanes) + PV
        float o[4][2];
        #pragma unroll
        for (int qa = 0; qa < 4; ++qa) {
            float mx = -3.0e38f;
            #pragma unroll
            for (int ka = 0; ka < 4; ++ka)
                mx = mka[ka] ? fmaxf(mx, t[qa * 4 + ka]) : mx;
            float e[4], ssum = 0.f;
            #pragma unroll
            for (int ka = 0; ka < 4; ++ka) {
                e[ka] = mka[ka] ? __expf(t[qa * 4 + ka] - mx) : 0.f;
                ssum += e[ka];
            }
            const float inv = ssum > 0.f ? 1.f / ssum : 0.f;
            float o0 = 0.f, o1 = 0.f;
            #pragma unroll
            for (int ka = 0; ka < 4; ++ka) {
                float w = e[ka] * inv;
                o0 += w * vv[ka][0];
                o1 += w * vv[ka][1];
            }
            o[qa][0] = o0; o[qa][1] = o1;
        }
        // scatter O to swizzled LDS: phys = row*128 + ((c8 ^ key(row&15))<<3) + j
        #pragma unroll
        for (int r = 0; r < 4; ++r) {
            const int row = m * 16 + quad * 4 + r;
            const int key = key_w ^ swz_key(r);   // swz_key is bitwise-separable
            #pragma unroll
            for (int nt = 0; nt < 2; ++nt) {
                const int col = wave * 32 + nt * 16 + lrow;
                const int c8 = col >> 3, j = col & 7;
                sO[row * CDIM + ((c8 ^ key) << 3) + j] = bf1(o[r][nt]);
            }
        }
    }
    __syncthreads();

    // ---- output projection: out = O @ Wo^T + bo, * residue_mask ------------
    f32x4 acc2[4][2];
    #pragma unroll
    for (int m = 0; m < 4; ++m)
        #pragma unroll
        for (int nt = 0; nt < 2; ++nt) acc2[m][nt] = vzero;

    const int key_r = swz_key(lrow);
    #pragma unroll
    for (int ks = 0; ks < 4; ++ks) {
        bf16x8 a2[4];
        #pragma unroll
        for (int m = 0; m < 4; ++m) {
            const int c8 = ks * 4 + quad;
            a2[m] = *(const bf16x8*)(sO + (m * 16 + lrow) * CDIM + ((c8 ^ key_r) << 3));
        }
        bf16x8 b2[2];
        #pragma unroll
        for (int nt = 0; nt < 2; ++nt) {
            int wrow = wave * 32 + nt * 16 + lrow;
            if constexpr (USEWS) {
                b2[nt] = *(const bf16x8*)(wbf + 3 * 16384 + wrow * CDIM + ks * 32 + quad * 8);
            } else {
                const float* wp = Wo + wrow * CDIM + ks * 32 + quad * 8;
                b2[nt] = pack8(((const float4*)wp)[0], ((const float4*)wp)[1]);
            }
        }
        #pragma unroll
        for (int m = 0; m < 4; ++m)
            #pragma unroll
            for (int nt = 0; nt < 2; ++nt)
                acc2[m][nt] = __builtin_amdgcn_mfma_f32_16x16x32_bf16(
                    a2[m], b2[nt], acc2[m][nt], 0, 0, 0);
    }
    {
        #pragma unroll
        for (int m = 0; m < 4; ++m) {
            const int4 mk2 = *(const int4*)(mask + ((long)blockIdx.x * RPB + m * 4 + quad) * 4);
            const float rm = (mk2.x | mk2.y | mk2.z | mk2.w) ? 1.f : 0.f;
            #pragma unroll
            for (int nt = 0; nt < 2; ++nt) {
                int col = wave * 32 + nt * 16 + lrow;
                float bb = bo[col];
                #pragma unroll
                for (int r = 0; r < 4; ++r) {
                    long row = m0 + m * 16 + quad * 4 + r;
                    out[row * CDIM + col] = (acc2[m][nt][r] + bb) * rm;
                }
            }
        }
    }
}

// ------------------------------- launcher -----------------------------------
extern "C" void kernel_launch(void* const* d_in, const int* in_sizes, int n_in,
                              void* d_out, int out_size, void* d_ws, size_t ws_size,
                              hipStream_t stream) {
    const float* x    = (const float*)d_in[0];
    const int*   mask = (const int*)d_in[1];
    const float* Wq   = (const float*)d_in[2];
    const float* bq   = (const float*)d_in[3];
    const float* Wk   = (const float*)d_in[4];
    const float* bk   = (const float*)d_in[5];
    const float* Wv   = (const float*)d_in[6];
    const float* bv   = (const float*)d_in[7];
    const float* Wo   = (const float*)d_in[8];
    const float* bo   = (const float*)d_in[9];
    float* out = (float*)d_out;

    const int nblocks = N_RES / RPB;   // 4096
    const bool usews = ws_size >= (size_t)(4 * 16384 * sizeof(uint16_t));
    if (usews) {
        uint16_t* wbf = (uint16_t*)d_ws;
        wconv_kernel<<<64, 256, 0, stream>>>(Wq, Wk, Wv, Wo, wbf);
        laa_main<true><<<nblocks, 256, 0, stream>>>(x, mask, Wq, bq, Wk, bk, Wv, bv,
                                                    Wo, bo, wbf, out);
    } else {
        laa_main<false><<<nblocks, 256, 0, stream>>>(x, mask, Wq, bq, Wk, bk, Wv, bv,
                                                     Wo, bo, nullptr, out);
    }
}